// Round 10
// baseline (3345.288 us; speedup 1.0000x reference)
//
#include <hip/hip_runtime.h>

// ---------------------------------------------------------------------------
// NetSEIR, fp32-exact path.
//   rates_z = sigmoid(relu(X @ W_z) @ w1_z), z in {beta,gamma,sigma}
//   then sequential SEIR scan (T-1 steps), output [4][T] fp32.
//
// Round-8 lesson: rates do NOT all saturate to 1.0 (row-sum of X dominates
// the pre-relu activations; ~10% of rows land in sigmoid's sensitive region).
// bf16 GEMM gave rate errors up to ~0.25 there; the SEIR map has an exact
// undamped -1 eigenvalue, so those errors persist -> absmax 2.1e5. Therefore:
// fp32 GEMM + np-exact scan arithmetic (true division, no fma contraction).
//
// Pipeline (ws ~2.1 MiB):
//   k_sgemm : fp32 128x128 tile GEMM (8x8 reg tiles) + fused relu*w1
//             column-reduce -> partials[z][nt][m] (24 planes, deterministic)
//   k_rates : sum 8 partials, sigmoid -> rate4[t] = (b, g, s, 0)
//   k_scan  : single-wave recurrence, np op order, IEEE div by N
//   k_final : scratch [T][4] -> out [4][T], t=0 initials
// ---------------------------------------------------------------------------

// ------------------- fused fp32 GEMM + relu*w1 reduce ----------------------
// grid (24, T/128): bx -> (z, nt); by -> m-tile. block 256 = 16x16 threads,
// each thread owns an 8x8 C sub-tile. A = X [T][1024], B = W_z [k][n] as-is.
__global__ __launch_bounds__(256) void k_sgemm(
    const float* __restrict__ X, const float* __restrict__ Wb,
    const float* __restrict__ Wg, const float* __restrict__ Ws,
    const float* __restrict__ w1b, const float* __restrict__ w1g,
    const float* __restrict__ w1s, float* __restrict__ partials, int T) {
  __shared__ float As[16][128];  // [k][m]
  __shared__ float Bs[16][128];  // [k][n]
  int tid = threadIdx.x;
  int bx = blockIdx.x;
  int z = bx >> 3, nt = bx & 7;
  int m0 = blockIdx.y << 7, n0 = nt << 7;
  const float* W = (z == 0) ? Wb : ((z == 1) ? Wg : Ws);
  const float* w1 = (z == 0) ? w1b : ((z == 1) ? w1g : w1s);

  int tx = tid & 15, ty = tid >> 4;  // C cols tx*8.., rows ty*8..
  int lr = tid >> 1;                 // A-load row 0..127
  int lc = (tid & 1) << 3;           // A-load col offset 0/8
  int bc = tid >> 4;                 // B-load k-row 0..15
  int bn = (tid & 15) << 3;          // B-load col offset

  float acc[8][8] = {};

  for (int k0 = 0; k0 < 1024; k0 += 16) {
    float4 a0 = *(const float4*)&X[(size_t)(m0 + lr) * 1024 + k0 + lc];
    float4 a1 = *(const float4*)&X[(size_t)(m0 + lr) * 1024 + k0 + lc + 4];
    float4 b0 = *(const float4*)&W[(size_t)(k0 + bc) * 1024 + n0 + bn];
    float4 b1 = *(const float4*)&W[(size_t)(k0 + bc) * 1024 + n0 + bn + 4];
    __syncthreads();  // prev iter's LDS reads complete before overwrite
    As[lc + 0][lr] = a0.x; As[lc + 1][lr] = a0.y;
    As[lc + 2][lr] = a0.z; As[lc + 3][lr] = a0.w;
    As[lc + 4][lr] = a1.x; As[lc + 5][lr] = a1.y;
    As[lc + 6][lr] = a1.z; As[lc + 7][lr] = a1.w;
    *(float4*)&Bs[bc][bn] = b0;
    *(float4*)&Bs[bc][bn + 4] = b1;
    __syncthreads();
#pragma unroll
    for (int kk = 0; kk < 16; ++kk) {
      float4 av0 = *(const float4*)&As[kk][ty * 8];
      float4 av1 = *(const float4*)&As[kk][ty * 8 + 4];
      float4 bv0 = *(const float4*)&Bs[kk][tx * 8];
      float4 bv1 = *(const float4*)&Bs[kk][tx * 8 + 4];
      float av[8] = {av0.x, av0.y, av0.z, av0.w, av1.x, av1.y, av1.z, av1.w};
      float bv[8] = {bv0.x, bv0.y, bv0.z, bv0.w, bv1.x, bv1.y, bv1.z, bv1.w};
#pragma unroll
      for (int i = 0; i < 8; ++i)
#pragma unroll
        for (int j = 0; j < 8; ++j) acc[i][j] = fmaf(av[i], bv[j], acc[i][j]);
    }
  }

  // epilogue: rs[i] = sum_j relu(acc[i][j]) * w1[n0+tx*8+j], reduce over tx
  float4 w1a = *(const float4*)&w1[n0 + tx * 8];
  float4 w1c = *(const float4*)&w1[n0 + tx * 8 + 4];
  float w1v[8] = {w1a.x, w1a.y, w1a.z, w1a.w, w1c.x, w1c.y, w1c.z, w1c.w};
  float rs[8];
#pragma unroll
  for (int i = 0; i < 8; ++i) {
    float s = 0.f;
#pragma unroll
    for (int j = 0; j < 8; ++j) s += fmaxf(acc[i][j], 0.f) * w1v[j];
    rs[i] = s;
  }
  // threads sharing ty are lanes differing in bits 0-3 (tx) of the same wave
#pragma unroll
  for (int off = 1; off < 16; off <<= 1)
#pragma unroll
    for (int i = 0; i < 8; ++i) rs[i] += __shfl_xor(rs[i], off, 64);
  if (tx == 0) {
    float* dst = partials + (size_t)(z * 8 + nt) * T + m0 + ty * 8;
#pragma unroll
    for (int i = 0; i < 8; ++i) dst[i] = rs[i];
  }
}

// -------------------- partials -> sigmoid -> (b,g,s) -----------------------
__global__ __launch_bounds__(256) void k_rates(const float* __restrict__ partials,
                                               float4* __restrict__ rate4, int T) {
  int t = blockIdx.x * 256 + threadIdx.x;
  if (t >= T) return;
  float pre[3];
#pragma unroll
  for (int z = 0; z < 3; ++z) {
    float s = 0.f;
#pragma unroll
    for (int nt = 0; nt < 8; ++nt) s += partials[(size_t)(z * 8 + nt) * T + t];
    pre[z] = s;
  }
  float b = 1.f / (1.f + expf(-pre[0]));   // beta
  float g = 1.f / (1.f + expf(-pre[1]));   // gamma
  float sg = 1.f / (1.f + expf(-pre[2]));  // sigma
  rate4[t] = make_float4(b, g, sg, 0.f);
}

// ---------------- sequential SEIR scan, np-exact arithmetic ----------------
__global__ __launch_bounds__(64) void k_scan(const float4* __restrict__ rate4,
                                             const float* __restrict__ S0p,
                                             const float* __restrict__ E0p,
                                             const float* __restrict__ I0p,
                                             const float* __restrict__ R0p,
                                             const float* __restrict__ Np,
                                             float4* __restrict__ seir4, int T) {
#pragma clang fp contract(off)
  float S = S0p[0], E = E0p[0], I = I0p[0], Ic = I0p[0], R = R0p[0];
  float N = Np[0];
  float4 rv = rate4[0];
  for (int t = 0; t < T - 1; ++t) {
    float4 rnext = rate4[t + 1];  // independent prefetch (t+1 <= T-1)
    float b = rv.x, g = rv.y, s = rv.z;
    float S_to_E = ((b * Ic) * S) / N;     // ref: b*Ic*S/N, left-assoc, IEEE div
    float E_to_I = s * E;
    float I_to_R = g * Ic;
    float S1 = S - S_to_E;
    float E1 = (E + S_to_E) - E_to_I;      // ref order
    float Ic1 = (I + E_to_I) - I_to_R;     // uses previous I
    float R1 = R + I_to_R;
    if (threadIdx.x == 0) seir4[t] = make_float4(S1, E1, E_to_I, R1);
    S = S1; E = E1; I = E_to_I; Ic = Ic1; R = R1; rv = rnext;
  }
}

// -------------------- scratch [T][4] -> out [4][T] -------------------------
__global__ __launch_bounds__(256) void k_final(const float4* __restrict__ seir4,
                                               const float* __restrict__ S0p,
                                               const float* __restrict__ E0p,
                                               const float* __restrict__ I0p,
                                               const float* __restrict__ R0p,
                                               float* __restrict__ out, int T) {
  int t = blockIdx.x * 256 + threadIdx.x;
  if (t == 0) {
    out[0] = S0p[0];
    out[T] = E0p[0];
    out[2 * T] = I0p[0];
    out[3 * T] = R0p[0];
  }
  if (t < T - 1) {
    float4 v = seir4[t];
    out[t + 1] = v.x;
    out[T + t + 1] = v.y;
    out[2 * T + t + 1] = v.z;
    out[3 * T + t + 1] = v.w;
  }
}

extern "C" void kernel_launch(void* const* d_in, const int* in_sizes, int n_in,
                              void* d_out, int out_size, void* d_ws, size_t ws_size,
                              hipStream_t stream) {
  const float* X   = (const float*)d_in[0];
  const float* Wb  = (const float*)d_in[1];
  const float* w1b = (const float*)d_in[2];
  const float* Wg  = (const float*)d_in[3];
  const float* w1g = (const float*)d_in[4];
  const float* Ws  = (const float*)d_in[5];
  const float* w1s = (const float*)d_in[6];
  const float* S0p = (const float*)d_in[7];
  const float* E0p = (const float*)d_in[8];
  const float* I0p = (const float*)d_in[9];
  const float* R0p = (const float*)d_in[10];
  const float* Np  = (const float*)d_in[11];
  float* out = (float*)d_out;

  const int T = in_sizes[0] / 1024;  // 16384

  // workspace: partials (24*T*4 B) | rate4 (16*T B) | seir4 (16*T B) ~ 2.1 MiB
  char* ws = (char*)d_ws;
  float* partials = (float*)ws;
  float4* rate4 = (float4*)(ws + (size_t)96 * T);
  float4* seir4 = (float4*)(ws + (size_t)96 * T + (size_t)16 * T);

  k_sgemm<<<dim3(24, T / 128), 256, 0, stream>>>(X, Wb, Wg, Ws, w1b, w1g, w1s,
                                                 partials, T);
  k_rates<<<(T + 255) / 256, 256, 0, stream>>>(partials, rate4, T);
  k_scan<<<1, 64, 0, stream>>>(rate4, S0p, E0p, I0p, R0p, Np, seir4, T);
  k_final<<<(T + 255) / 256, 256, 0, stream>>>(seir4, S0p, E0p, I0p, R0p, out, T);
}

// Round 11
// 2744.584 us; speedup vs baseline: 1.2189x; 1.2189x over previous
//
#include <hip/hip_runtime.h>

// ---------------------------------------------------------------------------
// NetSEIR, fp32 path (round-10: PASS, absmax 64, 3345 us; k_scan was 2200 us
// at 322 cyc/step -- exposed L2 latency + div in the dependent chain).
//
// Round-11 change (scan only, k_sgemm untouched):
//   * rates staged chunk-wise into registers: 64 lanes each hold one float4,
//     double-buffered; per-step broadcast via __shfl with static lane index
//     (hoistable off the critical path). No loads on the chain.
//   * div by N -> mul by precomputed 1/N (error ~1.5 ulp/step, budget 337x).
//   * scan stores directly to out[4][T] (k_final eliminated).
//
// Pipeline (ws ~1.6 MiB):
//   k_sgemm : fp32 128x128 tile GEMM (8x8 reg tiles) + fused relu*w1
//             column-reduce -> partials[z][nt][m] (24 planes, deterministic)
//   k_rates : sum 8 partials, sigmoid -> rate4[t] = (b, g, s, 0)
//   k_scan  : single-wave recurrence, np op order, writes out directly
// ---------------------------------------------------------------------------

// ------------------- fused fp32 GEMM + relu*w1 reduce ----------------------
// grid (24, T/128): bx -> (z, nt); by -> m-tile. block 256 = 16x16 threads,
// each thread owns an 8x8 C sub-tile. A = X [T][1024], B = W_z [k][n] as-is.
__global__ __launch_bounds__(256) void k_sgemm(
    const float* __restrict__ X, const float* __restrict__ Wb,
    const float* __restrict__ Wg, const float* __restrict__ Ws,
    const float* __restrict__ w1b, const float* __restrict__ w1g,
    const float* __restrict__ w1s, float* __restrict__ partials, int T) {
  __shared__ float As[16][128];  // [k][m]
  __shared__ float Bs[16][128];  // [k][n]
  int tid = threadIdx.x;
  int bx = blockIdx.x;
  int z = bx >> 3, nt = bx & 7;
  int m0 = blockIdx.y << 7, n0 = nt << 7;
  const float* W = (z == 0) ? Wb : ((z == 1) ? Wg : Ws);
  const float* w1 = (z == 0) ? w1b : ((z == 1) ? w1g : w1s);

  int tx = tid & 15, ty = tid >> 4;  // C cols tx*8.., rows ty*8..
  int lr = tid >> 1;                 // A-load row 0..127
  int lc = (tid & 1) << 3;           // A-load col offset 0/8
  int bc = tid >> 4;                 // B-load k-row 0..15
  int bn = (tid & 15) << 3;          // B-load col offset

  float acc[8][8] = {};

  for (int k0 = 0; k0 < 1024; k0 += 16) {
    float4 a0 = *(const float4*)&X[(size_t)(m0 + lr) * 1024 + k0 + lc];
    float4 a1 = *(const float4*)&X[(size_t)(m0 + lr) * 1024 + k0 + lc + 4];
    float4 b0 = *(const float4*)&W[(size_t)(k0 + bc) * 1024 + n0 + bn];
    float4 b1 = *(const float4*)&W[(size_t)(k0 + bc) * 1024 + n0 + bn + 4];
    __syncthreads();  // prev iter's LDS reads complete before overwrite
    As[lc + 0][lr] = a0.x; As[lc + 1][lr] = a0.y;
    As[lc + 2][lr] = a0.z; As[lc + 3][lr] = a0.w;
    As[lc + 4][lr] = a1.x; As[lc + 5][lr] = a1.y;
    As[lc + 6][lr] = a1.z; As[lc + 7][lr] = a1.w;
    *(float4*)&Bs[bc][bn] = b0;
    *(float4*)&Bs[bc][bn + 4] = b1;
    __syncthreads();
#pragma unroll
    for (int kk = 0; kk < 16; ++kk) {
      float4 av0 = *(const float4*)&As[kk][ty * 8];
      float4 av1 = *(const float4*)&As[kk][ty * 8 + 4];
      float4 bv0 = *(const float4*)&Bs[kk][tx * 8];
      float4 bv1 = *(const float4*)&Bs[kk][tx * 8 + 4];
      float av[8] = {av0.x, av0.y, av0.z, av0.w, av1.x, av1.y, av1.z, av1.w};
      float bv[8] = {bv0.x, bv0.y, bv0.z, bv0.w, bv1.x, bv1.y, bv1.z, bv1.w};
#pragma unroll
      for (int i = 0; i < 8; ++i)
#pragma unroll
        for (int j = 0; j < 8; ++j) acc[i][j] = fmaf(av[i], bv[j], acc[i][j]);
    }
  }

  // epilogue: rs[i] = sum_j relu(acc[i][j]) * w1[n0+tx*8+j], reduce over tx
  float4 w1a = *(const float4*)&w1[n0 + tx * 8];
  float4 w1c = *(const float4*)&w1[n0 + tx * 8 + 4];
  float w1v[8] = {w1a.x, w1a.y, w1a.z, w1a.w, w1c.x, w1c.y, w1c.z, w1c.w};
  float rs[8];
#pragma unroll
  for (int i = 0; i < 8; ++i) {
    float s = 0.f;
#pragma unroll
    for (int j = 0; j < 8; ++j) s += fmaxf(acc[i][j], 0.f) * w1v[j];
    rs[i] = s;
  }
  // threads sharing ty are lanes differing in bits 0-3 (tx) of the same wave
#pragma unroll
  for (int off = 1; off < 16; off <<= 1)
#pragma unroll
    for (int i = 0; i < 8; ++i) rs[i] += __shfl_xor(rs[i], off, 64);
  if (tx == 0) {
    float* dst = partials + (size_t)(z * 8 + nt) * T + m0 + ty * 8;
#pragma unroll
    for (int i = 0; i < 8; ++i) dst[i] = rs[i];
  }
}

// -------------------- partials -> sigmoid -> (b,g,s) -----------------------
__global__ __launch_bounds__(256) void k_rates(const float* __restrict__ partials,
                                               float4* __restrict__ rate4, int T) {
  int t = blockIdx.x * 256 + threadIdx.x;
  if (t >= T) return;
  float pre[3];
#pragma unroll
  for (int z = 0; z < 3; ++z) {
    float s = 0.f;
#pragma unroll
    for (int nt = 0; nt < 8; ++nt) s += partials[(size_t)(z * 8 + nt) * T + t];
    pre[z] = s;
  }
  float b = 1.f / (1.f + expf(-pre[0]));   // beta
  float g = 1.f / (1.f + expf(-pre[1]));   // gamma
  float sg = 1.f / (1.f + expf(-pre[2]));  // sigma
  rate4[t] = make_float4(b, g, sg, 0.f);
}

// ---------------- sequential SEIR scan, register-staged rates --------------
// 64 lanes hold one chunk (64 steps) of rates each; next chunk is loaded
// while the current one is consumed (~1300 cyc cover >> ~200-900 cyc lat).
// All lanes compute the identical scan (no divergence); lane 0 stores
// directly to out[4][T]. t=0 initials also written here.
__global__ __launch_bounds__(64) void k_scan(const float4* __restrict__ rate4,
                                             const float* __restrict__ S0p,
                                             const float* __restrict__ E0p,
                                             const float* __restrict__ I0p,
                                             const float* __restrict__ R0p,
                                             const float* __restrict__ Np,
                                             float* __restrict__ out, int T) {
#pragma clang fp contract(off)
  int lane = threadIdx.x;
  float S = S0p[0], E = E0p[0], I = I0p[0], Ic = I0p[0], R = R0p[0];
  float invN = 1.0f / Np[0];
  if (lane == 0) {
    out[0] = S;
    out[T] = E;
    out[2 * T] = I;
    out[3 * T] = R;
  }
  float* oS = out + 1;
  float* oE = out + T + 1;
  float* oI = out + 2 * T + 1;
  float* oR = out + 3 * T + 1;

  const int nsteps = T - 1;          // 16383
  const int nfull = nsteps >> 6;     // 255 full chunks of 64
  float4 cur = rate4[lane];          // chunk 0

#define SEIR_STEP(KK)                                                          \
  {                                                                            \
    float b = __shfl(cur.x, (KK), 64);                                         \
    float g = __shfl(cur.y, (KK), 64);                                         \
    float s = __shfl(cur.z, (KK), 64);                                         \
    float S_to_E = ((b * Ic) * S) * invN;                                      \
    float E_to_I = s * E;                                                      \
    float I_to_R = g * Ic;                                                     \
    float S1 = S - S_to_E;                                                     \
    float E1 = (E + S_to_E) - E_to_I;                                          \
    float Ic1 = (I + E_to_I) - I_to_R;                                         \
    float R1 = R + I_to_R;                                                     \
    if (lane == 0) {                                                           \
      oS[t + (KK)] = S1; oE[t + (KK)] = E1;                                    \
      oI[t + (KK)] = E_to_I; oR[t + (KK)] = R1;                                \
    }                                                                          \
    S = S1; E = E1; I = E_to_I; Ic = Ic1; R = R1;                              \
  }

  for (int c = 0; c < nfull; ++c) {
    float4 nxt = rate4[(c + 1) * 64 + lane];  // covered by 64 steps of compute
    int t = c * 64;
#pragma unroll
    for (int k = 0; k < 64; ++k) SEIR_STEP(k)
    cur = nxt;
  }
  // tail: steps nfull*64 .. nsteps-1 (63 steps), rates already in cur
  {
    int t = nfull * 64;
    int rem = nsteps - t;  // 63
#pragma unroll 1
    for (int k = 0; k < rem; ++k) SEIR_STEP(k)
  }
#undef SEIR_STEP
}

extern "C" void kernel_launch(void* const* d_in, const int* in_sizes, int n_in,
                              void* d_out, int out_size, void* d_ws, size_t ws_size,
                              hipStream_t stream) {
  const float* X   = (const float*)d_in[0];
  const float* Wb  = (const float*)d_in[1];
  const float* w1b = (const float*)d_in[2];
  const float* Wg  = (const float*)d_in[3];
  const float* w1g = (const float*)d_in[4];
  const float* Ws  = (const float*)d_in[5];
  const float* w1s = (const float*)d_in[6];
  const float* S0p = (const float*)d_in[7];
  const float* E0p = (const float*)d_in[8];
  const float* I0p = (const float*)d_in[9];
  const float* R0p = (const float*)d_in[10];
  const float* Np  = (const float*)d_in[11];
  float* out = (float*)d_out;

  const int T = in_sizes[0] / 1024;  // 16384

  // workspace: partials (24*T*4 B) | rate4 (16*T B)  ~ 1.8 MiB
  char* ws = (char*)d_ws;
  float* partials = (float*)ws;
  float4* rate4 = (float4*)(ws + (size_t)96 * T);

  k_sgemm<<<dim3(24, T / 128), 256, 0, stream>>>(X, Wb, Wg, Ws, w1b, w1g, w1s,
                                                 partials, T);
  k_rates<<<(T + 255) / 256, 256, 0, stream>>>(partials, rate4, T);
  k_scan<<<1, 64, 0, stream>>>(rate4, S0p, E0p, I0p, R0p, Np, out, T);
}

// Round 12
// 1905.580 us; speedup vs baseline: 1.7555x; 1.4403x over previous
//
#include <hip/hip_runtime.h>

// ---------------------------------------------------------------------------
// NetSEIR, fp32 path.
// R10: PASS 3345 us (scan 2200 us, 322 cyc/step: L2 latency + div on chain).
// R11: PASS 2745 us (scan 1622 us, 237 cyc/step). Post-mortem: __shfl =
//      ds_bpermute (LDS path, lgkmcnt waits) x3/step + exec-masked stores
//      x4/step dominate; single wave hides nothing.
// R12 (scan only; k_sgemm untouched):
//   * readlane (SGPR broadcast, no LDS) instead of __shfl
//   * per-step capture via cndmask; ONE coalesced store burst per 64 steps
//   * b*invN folded into k_rates (one fewer mul on the chain)
//
// Pipeline (ws ~1.8 MiB):
//   k_sgemm : fp32 128x128 tile GEMM (8x8 reg tiles) + fused relu*w1
//             column-reduce -> partials[z][nt][m] (24 planes, deterministic)
//   k_rates : sum 8 partials, sigmoid -> rate4[t] = (b/N, g, s, 0)
//   k_scan  : single-wave recurrence; writes out[4][T] directly
// ---------------------------------------------------------------------------

// ------------------- fused fp32 GEMM + relu*w1 reduce ----------------------
// grid (24, T/128): bx -> (z, nt); by -> m-tile. block 256 = 16x16 threads,
// each thread owns an 8x8 C sub-tile. A = X [T][1024], B = W_z [k][n] as-is.
__global__ __launch_bounds__(256) void k_sgemm(
    const float* __restrict__ X, const float* __restrict__ Wb,
    const float* __restrict__ Wg, const float* __restrict__ Ws,
    const float* __restrict__ w1b, const float* __restrict__ w1g,
    const float* __restrict__ w1s, float* __restrict__ partials, int T) {
  __shared__ float As[16][128];  // [k][m]
  __shared__ float Bs[16][128];  // [k][n]
  int tid = threadIdx.x;
  int bx = blockIdx.x;
  int z = bx >> 3, nt = bx & 7;
  int m0 = blockIdx.y << 7, n0 = nt << 7;
  const float* W = (z == 0) ? Wb : ((z == 1) ? Wg : Ws);
  const float* w1 = (z == 0) ? w1b : ((z == 1) ? w1g : w1s);

  int tx = tid & 15, ty = tid >> 4;  // C cols tx*8.., rows ty*8..
  int lr = tid >> 1;                 // A-load row 0..127
  int lc = (tid & 1) << 3;           // A-load col offset 0/8
  int bc = tid >> 4;                 // B-load k-row 0..15
  int bn = (tid & 15) << 3;          // B-load col offset

  float acc[8][8] = {};

  for (int k0 = 0; k0 < 1024; k0 += 16) {
    float4 a0 = *(const float4*)&X[(size_t)(m0 + lr) * 1024 + k0 + lc];
    float4 a1 = *(const float4*)&X[(size_t)(m0 + lr) * 1024 + k0 + lc + 4];
    float4 b0 = *(const float4*)&W[(size_t)(k0 + bc) * 1024 + n0 + bn];
    float4 b1 = *(const float4*)&W[(size_t)(k0 + bc) * 1024 + n0 + bn + 4];
    __syncthreads();  // prev iter's LDS reads complete before overwrite
    As[lc + 0][lr] = a0.x; As[lc + 1][lr] = a0.y;
    As[lc + 2][lr] = a0.z; As[lc + 3][lr] = a0.w;
    As[lc + 4][lr] = a1.x; As[lc + 5][lr] = a1.y;
    As[lc + 6][lr] = a1.z; As[lc + 7][lr] = a1.w;
    *(float4*)&Bs[bc][bn] = b0;
    *(float4*)&Bs[bc][bn + 4] = b1;
    __syncthreads();
#pragma unroll
    for (int kk = 0; kk < 16; ++kk) {
      float4 av0 = *(const float4*)&As[kk][ty * 8];
      float4 av1 = *(const float4*)&As[kk][ty * 8 + 4];
      float4 bv0 = *(const float4*)&Bs[kk][tx * 8];
      float4 bv1 = *(const float4*)&Bs[kk][tx * 8 + 4];
      float av[8] = {av0.x, av0.y, av0.z, av0.w, av1.x, av1.y, av1.z, av1.w};
      float bv[8] = {bv0.x, bv0.y, bv0.z, bv0.w, bv1.x, bv1.y, bv1.z, bv1.w};
#pragma unroll
      for (int i = 0; i < 8; ++i)
#pragma unroll
        for (int j = 0; j < 8; ++j) acc[i][j] = fmaf(av[i], bv[j], acc[i][j]);
    }
  }

  // epilogue: rs[i] = sum_j relu(acc[i][j]) * w1[n0+tx*8+j], reduce over tx
  float4 w1a = *(const float4*)&w1[n0 + tx * 8];
  float4 w1c = *(const float4*)&w1[n0 + tx * 8 + 4];
  float w1v[8] = {w1a.x, w1a.y, w1a.z, w1a.w, w1c.x, w1c.y, w1c.z, w1c.w};
  float rs[8];
#pragma unroll
  for (int i = 0; i < 8; ++i) {
    float s = 0.f;
#pragma unroll
    for (int j = 0; j < 8; ++j) s += fmaxf(acc[i][j], 0.f) * w1v[j];
    rs[i] = s;
  }
  // threads sharing ty are lanes differing in bits 0-3 (tx) of the same wave
#pragma unroll
  for (int off = 1; off < 16; off <<= 1)
#pragma unroll
    for (int i = 0; i < 8; ++i) rs[i] += __shfl_xor(rs[i], off, 64);
  if (tx == 0) {
    float* dst = partials + (size_t)(z * 8 + nt) * T + m0 + ty * 8;
#pragma unroll
    for (int i = 0; i < 8; ++i) dst[i] = rs[i];
  }
}

// ----------------- partials -> sigmoid -> (b/N, g, s) ----------------------
__global__ __launch_bounds__(256) void k_rates(const float* __restrict__ partials,
                                               const float* __restrict__ Np,
                                               float4* __restrict__ rate4, int T) {
  int t = blockIdx.x * 256 + threadIdx.x;
  if (t >= T) return;
  float pre[3];
#pragma unroll
  for (int z = 0; z < 3; ++z) {
    float s = 0.f;
#pragma unroll
    for (int nt = 0; nt < 8; ++nt) s += partials[(size_t)(z * 8 + nt) * T + t];
    pre[z] = s;
  }
  float invN = 1.0f / Np[0];
  float b = 1.f / (1.f + expf(-pre[0]));   // beta
  float g = 1.f / (1.f + expf(-pre[1]));   // gamma
  float sg = 1.f / (1.f + expf(-pre[2]));  // sigma
  rate4[t] = make_float4(b * invN, g, sg, 0.f);
}

// ---------------- sequential SEIR scan, readlane + burst stores ------------
// 64 lanes each hold one chunk-step's rate (double-buffered global loads).
// Broadcast via v_readlane (register file, no LDS). All lanes compute the
// identical scan; lane l captures step c*64+l via cndmask; one coalesced
// 4-store burst per chunk. No memory ops on the dependent chain.
__global__ __launch_bounds__(64) void k_scan(const float4* __restrict__ rate4,
                                             const float* __restrict__ S0p,
                                             const float* __restrict__ E0p,
                                             const float* __restrict__ I0p,
                                             const float* __restrict__ R0p,
                                             float* __restrict__ out, int T) {
#pragma clang fp contract(off)
  int lane = threadIdx.x;
  float S = S0p[0], E = E0p[0], I = I0p[0], Ic = I0p[0], R = R0p[0];
  if (lane == 0) {
    out[0] = S;
    out[T] = E;
    out[2 * T] = I;
    out[3 * T] = R;
  }
  float* oS = out + 1;
  float* oE = out + T + 1;
  float* oI = out + 2 * T + 1;
  float* oR = out + 3 * T + 1;

  const int nsteps = T - 1;          // 16383
  const int nfull = nsteps >> 6;     // 255 full chunks of 64
  float4 cur = rate4[lane];          // chunk 0
  float capS = 0.f, capE = 0.f, capI = 0.f, capR = 0.f;

#define RL(v, k) __uint_as_float(__builtin_amdgcn_readlane(__float_as_uint(v), (k)))
#define SEIR_STEP(KK)                                                          \
  {                                                                            \
    float bN = RL(cur.x, (KK));                                                \
    float g = RL(cur.y, (KK));                                                 \
    float s = RL(cur.z, (KK));                                                 \
    float S_to_E = (bN * Ic) * S;                                              \
    float E_to_I = s * E;                                                      \
    float I_to_R = g * Ic;                                                     \
    float S1 = S - S_to_E;                                                     \
    float E1 = (E + S_to_E) - E_to_I;                                          \
    float Ic1 = (I + E_to_I) - I_to_R;                                         \
    float R1 = R + I_to_R;                                                     \
    bool m = (lane == (KK));                                                   \
    capS = m ? S1 : capS;                                                      \
    capE = m ? E1 : capE;                                                      \
    capI = m ? E_to_I : capI;                                                  \
    capR = m ? R1 : capR;                                                      \
    S = S1; E = E1; I = E_to_I; Ic = Ic1; R = R1;                              \
  }

  for (int c = 0; c < nfull; ++c) {
    float4 nxt = rate4[(c + 1) * 64 + lane];  // covered by 64 steps of compute
#pragma unroll
    for (int k = 0; k < 64; ++k) SEIR_STEP(k)
    int t = c * 64 + lane;
    oS[t] = capS;
    oE[t] = capE;
    oI[t] = capI;
    oR[t] = capR;
    cur = nxt;
  }
  // tail: 63 steps (lanes 0..62 capture; lane 63 masked out of the store)
  {
    int rem = nsteps - nfull * 64;  // 63
#pragma unroll 1
    for (int k = 0; k < rem; ++k) SEIR_STEP(k)
    if (lane < rem) {
      int t = nfull * 64 + lane;
      oS[t] = capS;
      oE[t] = capE;
      oI[t] = capI;
      oR[t] = capR;
    }
  }
#undef SEIR_STEP
#undef RL
}

extern "C" void kernel_launch(void* const* d_in, const int* in_sizes, int n_in,
                              void* d_out, int out_size, void* d_ws, size_t ws_size,
                              hipStream_t stream) {
  const float* X   = (const float*)d_in[0];
  const float* Wb  = (const float*)d_in[1];
  const float* w1b = (const float*)d_in[2];
  const float* Wg  = (const float*)d_in[3];
  const float* w1g = (const float*)d_in[4];
  const float* Ws  = (const float*)d_in[5];
  const float* w1s = (const float*)d_in[6];
  const float* S0p = (const float*)d_in[7];
  const float* E0p = (const float*)d_in[8];
  const float* I0p = (const float*)d_in[9];
  const float* R0p = (const float*)d_in[10];
  const float* Np  = (const float*)d_in[11];
  float* out = (float*)d_out;

  const int T = in_sizes[0] / 1024;  // 16384

  // workspace: partials (24*T*4 B) | rate4 (16*T B)  ~ 1.8 MiB
  char* ws = (char*)d_ws;
  float* partials = (float*)ws;
  float4* rate4 = (float4*)(ws + (size_t)96 * T);

  k_sgemm<<<dim3(24, T / 128), 256, 0, stream>>>(X, Wb, Wg, Ws, w1b, w1g, w1s,
                                                 partials, T);
  k_rates<<<(T + 255) / 256, 256, 0, stream>>>(partials, Np, rate4, T);
  k_scan<<<1, 64, 0, stream>>>(rate4, S0p, E0p, I0p, R0p, out, T);
}